// Round 12
// baseline (872.985 us; speedup 1.0000x reference)
//
#include <hip/hip_runtime.h>
#include <hip/hip_bf16.h>

#define LOG2E 1.44269504088896340736f

typedef __attribute__((ext_vector_type(8))) short short8;
typedef __attribute__((ext_vector_type(2))) float f32x2;
typedef __attribute__((ext_vector_type(4))) float f32x4;
typedef __attribute__((ext_vector_type(16))) float f32x16;

__device__ __forceinline__ unsigned short f2bf(float f) {
    unsigned int u = __float_as_uint(f);
    u += 0x7fffu + ((u >> 16) & 1u);
    return (unsigned short)(u >> 16);
}

__device__ __forceinline__ unsigned cvt_pk_bf16(float a, float b) {
    unsigned r;
    asm("v_cvt_pk_bf16_f32 %0, %1, %2" : "=v"(r) : "v"(a), "v"(b));
    return r;   // low16 = bf16(a), high16 = bf16(b)
}

__device__ __forceinline__ float fast_exp2(float x) {
    float r;
    asm("v_exp_f32 %0, %1" : "=v"(r) : "v"(x));
    return r;
}

// async global(16B/lane) -> LDS (wave-uniform base + lane*16)
__device__ __forceinline__ void gl_lds16(const unsigned short* g, unsigned short* l) {
    __builtin_amdgcn_global_load_lds(
        (const __attribute__((address_space(1))) unsigned int*)g,
        (__attribute__((address_space(3))) unsigned int*)l, 16, 0, 0);
}

// ---------------- fp32 -> bf16 conversion, XOR-swizzled (ncols = 768) -------
// within each 64-col tile: 8-u16 slot' = slot ^ (row&7)
__global__ void cvt_swz(const float* __restrict__ in,
                        unsigned short* __restrict__ out, int n8) {
    int stride = gridDim.x * blockDim.x;
    for (int i = blockIdx.x * blockDim.x + threadIdx.x; i < n8; i += stride) {
        int flat = i * 8;
        int row = flat / 768;
        int col = flat - row * 768;
        float4 v0 = ((const float4*)(in + flat))[0];
        float4 v1 = ((const float4*)(in + flat))[1];
        union { unsigned short u[8]; short8 v; } o;
        o.u[0] = f2bf(v0.x); o.u[1] = f2bf(v0.y);
        o.u[2] = f2bf(v0.z); o.u[3] = f2bf(v0.w);
        o.u[4] = f2bf(v1.x); o.u[5] = f2bf(v1.y);
        o.u[6] = f2bf(v1.z); o.u[7] = f2bf(v1.w);
        int c = (col & 63) ^ ((row & 7) << 3);
        *(short8*)(out + (size_t)row * 768 + (col & ~63) + c) = o.v;
    }
}

// ---------------- GEMM: C[m][n] = sum_k A[m][k]*B[n][k] (+bias) ----------------
// A,B pre-swizzled in HBM; LDS linear dbuf via global_load_lds; 1 barrier/iter.
// EPI==0: scatter to qkv_sep; Q pre-scaled; K (N,hd) and V^T (hd,N) PLAIN.
// EPI==1: fp32 out (M x N).
template <int EPI, int BN>
__global__ __launch_bounds__(256, BN == 64 ? 3 : 2)
void gemm_bt(const unsigned short* __restrict__ A,
             const unsigned short* __restrict__ B,
             const float* __restrict__ bias,
             void* __restrict__ Cout,
             int M, int N, int K) {
    __shared__ unsigned short As[2][8192];      // [128][64] linear per buf
    __shared__ unsigned short Bs[2][BN * 64];
    constexpr int NB = BN / 32;                 // B frags per wave; B stage iters

    const int tid  = threadIdx.x;
    const int wave = tid >> 6, lane = tid & 63;
    const int fr = lane & 15, fg = lane >> 4;
    const int wm = (wave >> 1) * 64, wn = (wave & 1) * (BN / 2);
    const int m0 = blockIdx.y * 128, n0 = blockIdx.x * BN;
    const int sr = lane >> 3, ss = lane & 7;

    f32x4 acc[4][NB];
#pragma unroll
    for (int m = 0; m < 4; m++)
#pragma unroll
        for (int n = 0; n < NB; n++) acc[m][n] = (f32x4){0.f, 0.f, 0.f, 0.f};

    const int NT = K >> 6;

#define GEMM_STAGE(buf, k0)                                                     \
    {                                                                           \
        _Pragma("unroll")                                                       \
        for (int c = 0; c < 4; c++) {                                           \
            int rr = (c * 4 + wave) * 8 + sr;                                   \
            gl_lds16(A + (size_t)(m0 + rr) * K + (k0) + ss * 8,                 \
                     &As[buf][(c * 4 + wave) * 512]);                           \
        }                                                                       \
        _Pragma("unroll")                                                       \
        for (int c = 0; c < NB; c++) {                                          \
            int rr = (c * 4 + wave) * 8 + sr;                                   \
            gl_lds16(B + (size_t)(n0 + rr) * K + (k0) + ss * 8,                 \
                     &Bs[buf][(c * 4 + wave) * 512]);                           \
        }                                                                       \
    }

    GEMM_STAGE(0, 0)

    for (int t = 0; t < NT; t++) {
        __syncthreads();                       // drains DMA for tile t
        if (t + 1 < NT) GEMM_STAGE((t + 1) & 1, (t + 1) << 6)
        const unsigned short* ab = As[t & 1];
        const unsigned short* bb = Bs[t & 1];
        __builtin_amdgcn_s_setprio(1);
#pragma unroll
        for (int ks = 0; ks < 2; ks++) {
            short8 af[4], bfr[NB];
#pragma unroll
            for (int m = 0; m < 4; m++)
                af[m] = *(const short8*)&ab[(wm + m * 16 + fr) * 64 +
                                            (((ks * 4 + fg) ^ (fr & 7)) << 3)];
#pragma unroll
            for (int n = 0; n < NB; n++)
                bfr[n] = *(const short8*)&bb[(wn + n * 16 + fr) * 64 +
                                             (((ks * 4 + fg) ^ (fr & 7)) << 3)];
#pragma unroll
            for (int m = 0; m < 4; m++)
#pragma unroll
                for (int n = 0; n < NB; n++)
                    acc[m][n] = __builtin_amdgcn_mfma_f32_16x16x32_bf16(
                        af[m], bfr[n], acc[m][n], 0, 0, 0);
        }
        __builtin_amdgcn_s_setprio(0);
    }
#undef GEMM_STAGE

#pragma unroll
    for (int m = 0; m < 4; m++) {
#pragma unroll
        for (int n = 0; n < NB; n++) {
            int gn = n0 + wn + n * 16 + fr;
            float bv = bias[gn];
#pragma unroll
            for (int j = 0; j < 4; j++) {
                int gm = m0 + wm + m * 16 + fg * 4 + j;
                float v = acc[m][n][j] + bv;
                if (EPI == 0) {
                    int which = gn / 768, rem = gn % 768;
                    int h = rem >> 6, d = rem & 63;
                    int b = gm >> 12, nn = gm & 4095;
                    if (which == 0) v *= (0.125f * LOG2E);
                    unsigned short* o = (unsigned short*)Cout;
                    size_t base = (((size_t)which * 2 + b) * 12 + h) * 262144;
                    if (which == 2)
                        o[base + (size_t)d * 4096 + nn] = f2bf(v);   // V^T plain
                    else
                        o[base + (size_t)nn * 64 + d] = f2bf(v);     // Q,K plain
                } else {
                    float* o = (float*)Cout;
                    o[(size_t)gm * 768 + gn] = v;
                }
            }
        }
    }
}

// ---------------- Flash attention, KV-split=2 (r5-proven body) --------------
// Grid (32, 24, 2): blockIdx.z = kv split; each block does 32 KV tiles,
// writes UNNORMALIZED O^T (bf16, GEMM-A swizzled) + per-row (m, l).
// 6 blocks/CU -> 6 waves/SIMD for latency hiding.
__global__ __launch_bounds__(256, 6)
void attn_fwd(const unsigned short* __restrict__ qkv,
              unsigned short* __restrict__ o0,
              unsigned short* __restrict__ o1,
              float2* __restrict__ ml) {
    __shared__ unsigned short Ks[64][72];
    __shared__ unsigned short Vt[64][72];        // plain V^T: Vt[d][k]

    const int tid  = threadIdx.x;
    const int wave = tid >> 6, lane = tid & 63;
    const int l31 = lane & 31, hh = lane >> 5;
    const int l31p = (l31 & 0x13) | ((l31 & 4) << 1) | ((l31 & 8) >> 1); // b2<->b3

    const int qt = blockIdx.x;
    const int bh = blockIdx.y;
    const int s  = blockIdx.z;
    const int b = bh / 12, h = bh % 12;
    const int kt0 = s << 5;                      // 32 tiles per split
    unsigned short* dest = s ? o1 : o0;

    const size_t headsz = (size_t)4096 * 64;
    const unsigned short* qh  = qkv + ((size_t)b * 12 + h) * headsz;
    const unsigned short* kh  = qkv + ((size_t)(2 + b) * 12 + h) * headsz;
    const unsigned short* vht = qkv + ((size_t)(4 + b) * 12 + h) * headsz; // (hd,N)

    const int qw = qt * 128 + wave * 32;
    const int gq = qw + l31;

    // Q fragments (pre-scaled by 0.125*log2e): B-operand, 4 k-steps of 16
    short8 qf[4];
#pragma unroll
    for (int ks = 0; ks < 4; ks++)
        qf[ks] = *(const short8*)(qh + (size_t)gq * 64 + ks * 16 + hh * 8);

    float mrow = -1e30f, lrow = 0.f;
    f32x16 accA = (f32x16)0.f, accB = (f32x16)0.f;

    const int r = tid >> 3, sg = tid & 7;

    // pipeline prologue: loads for tile kt0
    short8 rK[2], rV[2];
#pragma unroll
    for (int c = 0; c < 2; c++) {
        int kr = r + c * 32;
        rK[c] = *(const short8*)(kh + (size_t)kt0 * 4096 + kr * 64 + sg * 8);
        rV[c] = *(const short8*)(vht + (size_t)kr * 4096 + kt0 * 64 + sg * 8);
    }

    for (int kt = kt0; kt < kt0 + 32; kt++) {
        __syncthreads();
#pragma unroll
        for (int c = 0; c < 2; c++) {
            int kr = r + c * 32;
            *(short8*)&Ks[kr][sg * 8] = rK[c];
            *(short8*)&Vt[kr][sg * 8] = rV[c];
        }
        if (kt + 1 < kt0 + 32) {
            const unsigned short* kb = kh + (size_t)(kt + 1) * 4096;
#pragma unroll
            for (int c = 0; c < 2; c++) {
                int kr = r + c * 32;
                rK[c] = *(const short8*)(kb + kr * 64 + sg * 8);
                rV[c] = *(const short8*)(vht + (size_t)kr * 4096 + (kt + 1) * 64 + sg * 8);
            }
        }
        __syncthreads();

        // S^T = K_perm x Q : two 32-k blocks, 4 k-steps each
        f32x16 s0 = (f32x16)0.f, s1 = (f32x16)0.f;
        __builtin_amdgcn_s_setprio(1);
#pragma unroll
        for (int ks = 0; ks < 4; ks++) {
            short8 kf0 = *(const short8*)&Ks[l31p][ks * 16 + hh * 8];
            short8 kf1 = *(const short8*)&Ks[32 + l31p][ks * 16 + hh * 8];
            s0 = __builtin_amdgcn_mfma_f32_32x32x16_bf16(kf0, qf[ks], s0, 0, 0, 0);
            s1 = __builtin_amdgcn_mfma_f32_32x32x16_bf16(kf1, qf[ks], s1, 0, 0, 0);
        }
        __builtin_amdgcn_s_setprio(0);

        // lane-local softmax over the 32 s-values (one q-row per lane)
        float t[16];
#pragma unroll
        for (int i = 0; i < 8; i++) t[i] = fmaxf(s0[2 * i], s0[2 * i + 1]);
#pragma unroll
        for (int i = 0; i < 8; i++) t[i + 8] = fmaxf(s1[2 * i], s1[2 * i + 1]);
#pragma unroll
        for (int w = 8; w; w >>= 1)
#pragma unroll
            for (int i = 0; i < 8; i++)
                if (i < w) t[i] = fmaxf(t[i], t[i + w]);
        float mx = fmaxf(t[0], __shfl_xor(t[0], 32));

        if (!__all(mx - mrow <= 8.0f)) {      // rare rescale path
            float mnew = fmaxf(mrow, mx);
            float corr = fast_exp2(mrow - mnew);
            mrow = mnew;
            lrow *= corr;
#pragma unroll
            for (int i = 0; i < 16; i++) { accA[i] *= corr; accB[i] *= corr; }
        }
#pragma unroll
        for (int i = 0; i < 16; i++) {
            s0[i] = fast_exp2(s0[i] - mrow);
            s1[i] = fast_exp2(s1[i] - mrow);
        }
#pragma unroll
        for (int i = 0; i < 8; i++) t[i] = s0[2 * i] + s0[2 * i + 1];
#pragma unroll
        for (int i = 0; i < 8; i++) t[i + 8] = s1[2 * i] + s1[2 * i + 1];
#pragma unroll
        for (int w = 8; w; w >>= 1)
#pragma unroll
            for (int i = 0; i < 8; i++)
                if (i < w) t[i] += t[i + w];
        lrow += t[0] + __shfl_xor(t[0], 32);

        // pack P: pf[ks2] covers k = 16*ks2 + 8*hh + e
        short8 pf[4];
        {
            union { unsigned w[4]; short8 v; } up;
            up.w[0] = cvt_pk_bf16(s0[0], s0[1]);  up.w[1] = cvt_pk_bf16(s0[2], s0[3]);
            up.w[2] = cvt_pk_bf16(s0[4], s0[5]);  up.w[3] = cvt_pk_bf16(s0[6], s0[7]);
            pf[0] = up.v;
            up.w[0] = cvt_pk_bf16(s0[8], s0[9]);  up.w[1] = cvt_pk_bf16(s0[10], s0[11]);
            up.w[2] = cvt_pk_bf16(s0[12], s0[13]); up.w[3] = cvt_pk_bf16(s0[14], s0[15]);
            pf[1] = up.v;
            up.w[0] = cvt_pk_bf16(s1[0], s1[1]);  up.w[1] = cvt_pk_bf16(s1[2], s1[3]);
            up.w[2] = cvt_pk_bf16(s1[4], s1[5]);  up.w[3] = cvt_pk_bf16(s1[6], s1[7]);
            pf[2] = up.v;
            up.w[0] = cvt_pk_bf16(s1[8], s1[9]);  up.w[1] = cvt_pk_bf16(s1[10], s1[11]);
            up.w[2] = cvt_pk_bf16(s1[12], s1[13]); up.w[3] = cvt_pk_bf16(s1[14], s1[15]);
            pf[3] = up.v;
        }

        // O^T += V^T x P
        __builtin_amdgcn_s_setprio(1);
#pragma unroll
        for (int ks2 = 0; ks2 < 4; ks2++) {
            short8 vf0 = *(const short8*)&Vt[l31][ks2 * 16 + hh * 8];
            short8 vf1 = *(const short8*)&Vt[32 + l31][ks2 * 16 + hh * 8];
            accA = __builtin_amdgcn_mfma_f32_32x32x16_bf16(vf0, pf[ks2], accA, 0, 0, 0);
            accB = __builtin_amdgcn_mfma_f32_32x32x16_bf16(vf1, pf[ks2], accB, 0, 0, 0);
        }
        __builtin_amdgcn_s_setprio(0);
    }

    // per-row (m, l): identical in both half-lanes; write once
    if (hh == 0)
        ml[((size_t)(s * 2 + b) * 12 + h) * 4096 + gq] = make_float2(mrow, lrow);

    // epilogue: UNNORMALIZED O^T, swizzled as GEMM-A operand (slot ^= row&7)
    size_t rowoff = (size_t)(b * 4096 + gq) * 768 + h * 64;
    int sw = l31 & 7;
#pragma unroll
    for (int g = 0; g < 4; g++) {
        ushort4 o;
        o.x = f2bf(accA[4 * g + 0]);
        o.y = f2bf(accA[4 * g + 1]);
        o.z = f2bf(accA[4 * g + 2]);
        o.w = f2bf(accA[4 * g + 3]);
        *(ushort4*)(dest + rowoff + ((g ^ sw) * 8) + hh * 4) = o;
        o.x = f2bf(accB[4 * g + 0]);
        o.y = f2bf(accB[4 * g + 1]);
        o.z = f2bf(accB[4 * g + 2]);
        o.w = f2bf(accB[4 * g + 3]);
        *(ushort4*)(dest + rowoff + (((4 + g) ^ sw) * 8) + hh * 4) = o;
    }
}

// ---------------- combine: att = merge(split0, split1) element-wise ---------
__global__ void attn_combine(unsigned short* __restrict__ o0,
                             const unsigned short* __restrict__ o1,
                             const float2* __restrict__ ml, int n8) {
    int stride = gridDim.x * blockDim.x;
    for (int i = blockIdx.x * blockDim.x + threadIdx.x; i < n8; i += stride) {
        int flat = i * 8;
        int row = flat / 768;                  // b*4096 + q
        int col = flat - row * 768;
        int h = col >> 6;
        int b = row >> 12, q = row & 4095;
        int base = (b * 12 + h) * 4096 + q;
        float2 a0 = ml[base];
        float2 a1 = ml[98304 + base];          // 2*12*4096 per split
        float m = fmaxf(a0.x, a1.x);
        float c0 = fast_exp2(a0.x - m), c1 = fast_exp2(a1.x - m);
        float inv = 1.0f / (c0 * a0.y + c1 * a1.y);
        float w0 = c0 * inv, w1 = c1 * inv;
        short8 v0 = *(const short8*)(o0 + flat);
        short8 v1 = *(const short8*)(o1 + flat);
        union { unsigned short u[8]; short8 v; } o;
#pragma unroll
        for (int j = 0; j < 8; j++) {
            float f0 = __uint_as_float(((unsigned)(unsigned short)v0[j]) << 16);
            float f1 = __uint_as_float(((unsigned)(unsigned short)v1[j]) << 16);
            o.u[j] = f2bf(w0 * f0 + w1 * f1);
        }
        *(short8*)(o0 + flat) = o.v;
    }
}

// ---------------- launch ----------------
extern "C" void kernel_launch(void* const* d_in, const int* in_sizes, int n_in,
                              void* d_out, int out_size, void* d_ws, size_t ws_size,
                              hipStream_t stream) {
    const float* x      = (const float*)d_in[0];
    const float* qkv_w  = (const float*)d_in[1];
    const float* qkv_b  = (const float*)d_in[2];
    const float* proj_w = (const float*)d_in[3];
    const float* proj_b = (const float*)d_in[4];
    float* out = (float*)d_out;

    char* ws = (char*)d_ws;
    unsigned short* x_bf    = (unsigned short*)(ws);              // 12,582,912 B
    unsigned short* w1_bf   = (unsigned short*)(ws + 12582912);   //  3,538,944 B
    unsigned short* w2_bf   = (unsigned short*)(ws + 16121856);   //  1,179,648 B
    unsigned short* qkv_sep = (unsigned short*)(ws + 17301504);   // 37,748,736 B
    unsigned short* att     = (unsigned short*)(ws + 55050240);   // 12,582,912 B

    // after gemm<0>, x_bf and w1_bf are dead -> reuse for split-1 partial + (m,l)
    unsigned short* o_part1 = x_bf;
    float2*         ml      = (float2*)w1_bf;   // 2*2*12*4096*8 B = 1.57 MB

    cvt_swz<<<2048, 256, 0, stream>>>(x,      x_bf,  6291456 / 8);
    cvt_swz<<<864,  256, 0, stream>>>(qkv_w,  w1_bf, 1769472 / 8);
    cvt_swz<<<288,  256, 0, stream>>>(proj_w, w2_bf,  589824 / 8);

    gemm_bt<0, 128><<<dim3(18, 64), 256, 0, stream>>>(x_bf, w1_bf, qkv_b, qkv_sep,
                                                      8192, 2304, 768);

    attn_fwd<<<dim3(32, 24, 2), 256, 0, stream>>>(qkv_sep, att, o_part1, ml);
    attn_combine<<<2048, 256, 0, stream>>>(att, o_part1, ml, 6291456 / 8);

    gemm_bt<1, 64><<<dim3(12, 64), 256, 0, stream>>>(att, w2_bf, proj_b, out,
                                                     8192, 768, 768);
}

// Round 13
// 236.394 us; speedup vs baseline: 3.6929x; 3.6929x over previous
//
#include <hip/hip_runtime.h>
#include <hip/hip_bf16.h>

#define LOG2E 1.44269504088896340736f

typedef __attribute__((ext_vector_type(8))) short short8;
typedef __attribute__((ext_vector_type(2))) float f32x2;
typedef __attribute__((ext_vector_type(4))) float f32x4;
typedef __attribute__((ext_vector_type(16))) float f32x16;

__device__ __forceinline__ unsigned short f2bf(float f) {
    unsigned int u = __float_as_uint(f);
    u += 0x7fffu + ((u >> 16) & 1u);
    return (unsigned short)(u >> 16);
}

__device__ __forceinline__ unsigned cvt_pk_bf16(float a, float b) {
    unsigned r;
    asm("v_cvt_pk_bf16_f32 %0, %1, %2" : "=v"(r) : "v"(a), "v"(b));
    return r;   // low16 = bf16(a), high16 = bf16(b)
}

__device__ __forceinline__ float fast_exp2(float x) {
    float r;
    asm("v_exp_f32 %0, %1" : "=v"(r) : "v"(x));
    return r;
}

// async global(16B/lane) -> LDS (wave-uniform base + lane*16)
__device__ __forceinline__ void gl_lds16(const unsigned short* g, unsigned short* l) {
    __builtin_amdgcn_global_load_lds(
        (const __attribute__((address_space(1))) unsigned int*)g,
        (__attribute__((address_space(3))) unsigned int*)l, 16, 0, 0);
}

// ---------------- fp32 -> bf16 conversion, XOR-swizzled (ncols = 768) -------
// within each 64-col tile: 8-u16 slot' = slot ^ (row&7)
__global__ void cvt_swz(const float* __restrict__ in,
                        unsigned short* __restrict__ out, int n8) {
    int stride = gridDim.x * blockDim.x;
    for (int i = blockIdx.x * blockDim.x + threadIdx.x; i < n8; i += stride) {
        int flat = i * 8;
        int row = flat / 768;
        int col = flat - row * 768;
        float4 v0 = ((const float4*)(in + flat))[0];
        float4 v1 = ((const float4*)(in + flat))[1];
        union { unsigned short u[8]; short8 v; } o;
        o.u[0] = f2bf(v0.x); o.u[1] = f2bf(v0.y);
        o.u[2] = f2bf(v0.z); o.u[3] = f2bf(v0.w);
        o.u[4] = f2bf(v1.x); o.u[5] = f2bf(v1.y);
        o.u[6] = f2bf(v1.z); o.u[7] = f2bf(v1.w);
        int c = (col & 63) ^ ((row & 7) << 3);
        *(short8*)(out + (size_t)row * 768 + (col & ~63) + c) = o.v;
    }
}

// ---------------- GEMM: C[m][n] = sum_k A[m][k]*B[n][k] (+bias) ----------------
// A,B pre-swizzled in HBM; LDS linear dbuf via global_load_lds; 1 barrier/iter.
// EPI==0: scatter to qkv_sep; Q pre-scaled; K (N,hd) and V^T (hd,N) PLAIN.
// EPI==1: fp32 out (M x N).
template <int EPI, int BN>
__global__ __launch_bounds__(256, BN == 64 ? 3 : 2)
void gemm_bt(const unsigned short* __restrict__ A,
             const unsigned short* __restrict__ B,
             const float* __restrict__ bias,
             void* __restrict__ Cout,
             int M, int N, int K) {
    __shared__ unsigned short As[2][8192];      // [128][64] linear per buf
    __shared__ unsigned short Bs[2][BN * 64];
    constexpr int NB = BN / 32;                 // B frags per wave; B stage iters

    const int tid  = threadIdx.x;
    const int wave = tid >> 6, lane = tid & 63;
    const int fr = lane & 15, fg = lane >> 4;
    const int wm = (wave >> 1) * 64, wn = (wave & 1) * (BN / 2);
    const int m0 = blockIdx.y * 128, n0 = blockIdx.x * BN;
    const int sr = lane >> 3, ss = lane & 7;

    f32x4 acc[4][NB];
#pragma unroll
    for (int m = 0; m < 4; m++)
#pragma unroll
        for (int n = 0; n < NB; n++) acc[m][n] = (f32x4){0.f, 0.f, 0.f, 0.f};

    const int NT = K >> 6;

#define GEMM_STAGE(buf, k0)                                                     \
    {                                                                           \
        _Pragma("unroll")                                                       \
        for (int c = 0; c < 4; c++) {                                           \
            int rr = (c * 4 + wave) * 8 + sr;                                   \
            gl_lds16(A + (size_t)(m0 + rr) * K + (k0) + ss * 8,                 \
                     &As[buf][(c * 4 + wave) * 512]);                           \
        }                                                                       \
        _Pragma("unroll")                                                       \
        for (int c = 0; c < NB; c++) {                                          \
            int rr = (c * 4 + wave) * 8 + sr;                                   \
            gl_lds16(B + (size_t)(n0 + rr) * K + (k0) + ss * 8,                 \
                     &Bs[buf][(c * 4 + wave) * 512]);                           \
        }                                                                       \
    }

    GEMM_STAGE(0, 0)

    for (int t = 0; t < NT; t++) {
        __syncthreads();                       // drains DMA for tile t
        if (t + 1 < NT) GEMM_STAGE((t + 1) & 1, (t + 1) << 6)
        const unsigned short* ab = As[t & 1];
        const unsigned short* bb = Bs[t & 1];
        __builtin_amdgcn_s_setprio(1);
#pragma unroll
        for (int ks = 0; ks < 2; ks++) {
            short8 af[4], bfr[NB];
#pragma unroll
            for (int m = 0; m < 4; m++)
                af[m] = *(const short8*)&ab[(wm + m * 16 + fr) * 64 +
                                            (((ks * 4 + fg) ^ (fr & 7)) << 3)];
#pragma unroll
            for (int n = 0; n < NB; n++)
                bfr[n] = *(const short8*)&bb[(wn + n * 16 + fr) * 64 +
                                             (((ks * 4 + fg) ^ (fr & 7)) << 3)];
#pragma unroll
            for (int m = 0; m < 4; m++)
#pragma unroll
                for (int n = 0; n < NB; n++)
                    acc[m][n] = __builtin_amdgcn_mfma_f32_16x16x32_bf16(
                        af[m], bfr[n], acc[m][n], 0, 0, 0);
        }
        __builtin_amdgcn_s_setprio(0);
    }
#undef GEMM_STAGE

#pragma unroll
    for (int m = 0; m < 4; m++) {
#pragma unroll
        for (int n = 0; n < NB; n++) {
            int gn = n0 + wn + n * 16 + fr;
            float bv = bias[gn];
#pragma unroll
            for (int j = 0; j < 4; j++) {
                int gm = m0 + wm + m * 16 + fg * 4 + j;
                float v = acc[m][n][j] + bv;
                if (EPI == 0) {
                    int which = gn / 768, rem = gn % 768;
                    int h = rem >> 6, d = rem & 63;
                    int b = gm >> 12, nn = gm & 4095;
                    if (which == 0) v *= (0.125f * LOG2E);
                    unsigned short* o = (unsigned short*)Cout;
                    size_t base = (((size_t)which * 2 + b) * 12 + h) * 262144;
                    if (which == 2)
                        o[base + (size_t)d * 4096 + nn] = f2bf(v);   // V^T plain
                    else
                        o[base + (size_t)nn * 64 + d] = f2bf(v);     // Q,K plain
                } else {
                    float* o = (float*)Cout;
                    o[(size_t)gm * 768 + gn] = v;
                }
            }
        }
    }
}

// ---------------- Flash attention, KV-split=2 (r5-proven body) --------------
// Grid (32, 24, 2): blockIdx.z = kv split; each block does 32 KV tiles,
// writes UNNORMALIZED O^T (bf16, GEMM-A swizzled) + per-row (m, l).
// launch_bounds (256,4): VGPR cap 128 -- (256,6) forced a 40-VGPR fit and
// spilled 3.7 GB to scratch in R12.
__global__ __launch_bounds__(256, 4)
void attn_fwd(const unsigned short* __restrict__ qkv,
              unsigned short* __restrict__ o0,
              unsigned short* __restrict__ o1,
              float2* __restrict__ ml) {
    __shared__ unsigned short Ks[64][72];
    __shared__ unsigned short Vt[64][72];        // plain V^T: Vt[d][k]

    const int tid  = threadIdx.x;
    const int wave = tid >> 6, lane = tid & 63;
    const int l31 = lane & 31, hh = lane >> 5;
    const int l31p = (l31 & 0x13) | ((l31 & 4) << 1) | ((l31 & 8) >> 1); // b2<->b3

    const int qt = blockIdx.x;
    const int bh = blockIdx.y;
    const int s  = blockIdx.z;
    const int b = bh / 12, h = bh % 12;
    const int kt0 = s << 5;                      // 32 tiles per split
    unsigned short* dest = s ? o1 : o0;

    const size_t headsz = (size_t)4096 * 64;
    const unsigned short* qh  = qkv + ((size_t)b * 12 + h) * headsz;
    const unsigned short* kh  = qkv + ((size_t)(2 + b) * 12 + h) * headsz;
    const unsigned short* vht = qkv + ((size_t)(4 + b) * 12 + h) * headsz; // (hd,N)

    const int qw = qt * 128 + wave * 32;
    const int gq = qw + l31;

    // Q fragments (pre-scaled by 0.125*log2e): B-operand, 4 k-steps of 16
    short8 qf[4];
#pragma unroll
    for (int ks = 0; ks < 4; ks++)
        qf[ks] = *(const short8*)(qh + (size_t)gq * 64 + ks * 16 + hh * 8);

    float mrow = -1e30f, lrow = 0.f;
    f32x16 accA = (f32x16)0.f, accB = (f32x16)0.f;

    const int r = tid >> 3, sg = tid & 7;

    // pipeline prologue: loads for tile kt0
    short8 rK[2], rV[2];
#pragma unroll
    for (int c = 0; c < 2; c++) {
        int kr = r + c * 32;
        rK[c] = *(const short8*)(kh + (size_t)kt0 * 4096 + kr * 64 + sg * 8);
        rV[c] = *(const short8*)(vht + (size_t)kr * 4096 + kt0 * 64 + sg * 8);
    }

    for (int kt = kt0; kt < kt0 + 32; kt++) {
        __syncthreads();
#pragma unroll
        for (int c = 0; c < 2; c++) {
            int kr = r + c * 32;
            *(short8*)&Ks[kr][sg * 8] = rK[c];
            *(short8*)&Vt[kr][sg * 8] = rV[c];
        }
        if (kt + 1 < kt0 + 32) {
            const unsigned short* kb = kh + (size_t)(kt + 1) * 4096;
#pragma unroll
            for (int c = 0; c < 2; c++) {
                int kr = r + c * 32;
                rK[c] = *(const short8*)(kb + kr * 64 + sg * 8);
                rV[c] = *(const short8*)(vht + (size_t)kr * 4096 + (kt + 1) * 64 + sg * 8);
            }
        }
        __syncthreads();

        // S^T = K_perm x Q : two 32-k blocks, 4 k-steps each
        f32x16 s0 = (f32x16)0.f, s1 = (f32x16)0.f;
        __builtin_amdgcn_s_setprio(1);
#pragma unroll
        for (int ks = 0; ks < 4; ks++) {
            short8 kf0 = *(const short8*)&Ks[l31p][ks * 16 + hh * 8];
            short8 kf1 = *(const short8*)&Ks[32 + l31p][ks * 16 + hh * 8];
            s0 = __builtin_amdgcn_mfma_f32_32x32x16_bf16(kf0, qf[ks], s0, 0, 0, 0);
            s1 = __builtin_amdgcn_mfma_f32_32x32x16_bf16(kf1, qf[ks], s1, 0, 0, 0);
        }
        __builtin_amdgcn_s_setprio(0);

        // lane-local softmax over the 32 s-values (one q-row per lane)
        float t[16];
#pragma unroll
        for (int i = 0; i < 8; i++) t[i] = fmaxf(s0[2 * i], s0[2 * i + 1]);
#pragma unroll
        for (int i = 0; i < 8; i++) t[i + 8] = fmaxf(s1[2 * i], s1[2 * i + 1]);
#pragma unroll
        for (int w = 8; w; w >>= 1)
#pragma unroll
            for (int i = 0; i < 8; i++)
                if (i < w) t[i] = fmaxf(t[i], t[i + w]);
        float mx = fmaxf(t[0], __shfl_xor(t[0], 32));

        if (!__all(mx - mrow <= 8.0f)) {      // rare rescale path
            float mnew = fmaxf(mrow, mx);
            float corr = fast_exp2(mrow - mnew);
            mrow = mnew;
            lrow *= corr;
#pragma unroll
            for (int i = 0; i < 16; i++) { accA[i] *= corr; accB[i] *= corr; }
        }
#pragma unroll
        for (int i = 0; i < 16; i++) {
            s0[i] = fast_exp2(s0[i] - mrow);
            s1[i] = fast_exp2(s1[i] - mrow);
        }
#pragma unroll
        for (int i = 0; i < 8; i++) t[i] = s0[2 * i] + s0[2 * i + 1];
#pragma unroll
        for (int i = 0; i < 8; i++) t[i + 8] = s1[2 * i] + s1[2 * i + 1];
#pragma unroll
        for (int w = 8; w; w >>= 1)
#pragma unroll
            for (int i = 0; i < 8; i++)
                if (i < w) t[i] += t[i + w];
        lrow += t[0] + __shfl_xor(t[0], 32);

        // pack P: pf[ks2] covers k = 16*ks2 + 8*hh + e
        short8 pf[4];
        {
            union { unsigned w[4]; short8 v; } up;
            up.w[0] = cvt_pk_bf16(s0[0], s0[1]);  up.w[1] = cvt_pk_bf16(s0[2], s0[3]);
            up.w[2] = cvt_pk_bf16(s0[4], s0[5]);  up.w[3] = cvt_pk_bf16(s0[6], s0[7]);
            pf[0] = up.v;
            up.w[0] = cvt_pk_bf16(s0[8], s0[9]);  up.w[1] = cvt_pk_bf16(s0[10], s0[11]);
            up.w[2] = cvt_pk_bf16(s0[12], s0[13]); up.w[3] = cvt_pk_bf16(s0[14], s0[15]);
            pf[1] = up.v;
            up.w[0] = cvt_pk_bf16(s1[0], s1[1]);  up.w[1] = cvt_pk_bf16(s1[2], s1[3]);
            up.w[2] = cvt_pk_bf16(s1[4], s1[5]);  up.w[3] = cvt_pk_bf16(s1[6], s1[7]);
            pf[2] = up.v;
            up.w[0] = cvt_pk_bf16(s1[8], s1[9]);  up.w[1] = cvt_pk_bf16(s1[10], s1[11]);
            up.w[2] = cvt_pk_bf16(s1[12], s1[13]); up.w[3] = cvt_pk_bf16(s1[14], s1[15]);
            pf[3] = up.v;
        }

        // O^T += V^T x P
        __builtin_amdgcn_s_setprio(1);
#pragma unroll
        for (int ks2 = 0; ks2 < 4; ks2++) {
            short8 vf0 = *(const short8*)&Vt[l31][ks2 * 16 + hh * 8];
            short8 vf1 = *(const short8*)&Vt[32 + l31][ks2 * 16 + hh * 8];
            accA = __builtin_amdgcn_mfma_f32_32x32x16_bf16(vf0, pf[ks2], accA, 0, 0, 0);
            accB = __builtin_amdgcn_mfma_f32_32x32x16_bf16(vf1, pf[ks2], accB, 0, 0, 0);
        }
        __builtin_amdgcn_s_setprio(0);
    }

    // per-row (m, l): identical in both half-lanes; write once
    if (hh == 0)
        ml[((size_t)(s * 2 + b) * 12 + h) * 4096 + gq] = make_float2(mrow, lrow);

    // epilogue: UNNORMALIZED O^T, swizzled as GEMM-A operand (slot ^= row&7)
    size_t rowoff = (size_t)(b * 4096 + gq) * 768 + h * 64;
    int sw = l31 & 7;
#pragma unroll
    for (int g = 0; g < 4; g++) {
        ushort4 o;
        o.x = f2bf(accA[4 * g + 0]);
        o.y = f2bf(accA[4 * g + 1]);
        o.z = f2bf(accA[4 * g + 2]);
        o.w = f2bf(accA[4 * g + 3]);
        *(ushort4*)(dest + rowoff + ((g ^ sw) * 8) + hh * 4) = o;
        o.x = f2bf(accB[4 * g + 0]);
        o.y = f2bf(accB[4 * g + 1]);
        o.z = f2bf(accB[4 * g + 2]);
        o.w = f2bf(accB[4 * g + 3]);
        *(ushort4*)(dest + rowoff + (((4 + g) ^ sw) * 8) + hh * 4) = o;
    }
}

// ---------------- combine: att = merge(split0, split1) element-wise ---------
__global__ void attn_combine(unsigned short* __restrict__ o0,
                             const unsigned short* __restrict__ o1,
                             const float2* __restrict__ ml, int n8) {
    int stride = gridDim.x * blockDim.x;
    for (int i = blockIdx.x * blockDim.x + threadIdx.x; i < n8; i += stride) {
        int flat = i * 8;
        int row = flat / 768;                  // b*4096 + q
        int col = flat - row * 768;
        int h = col >> 6;
        int b = row >> 12, q = row & 4095;
        int base = (b * 12 + h) * 4096 + q;
        float2 a0 = ml[base];
        float2 a1 = ml[98304 + base];          // 2*12*4096 per split
        float m = fmaxf(a0.x, a1.x);
        float c0 = fast_exp2(a0.x - m), c1 = fast_exp2(a1.x - m);
        float inv = 1.0f / (c0 * a0.y + c1 * a1.y);
        float w0 = c0 * inv, w1 = c1 * inv;
        short8 v0 = *(const short8*)(o0 + flat);
        short8 v1 = *(const short8*)(o1 + flat);
        union { unsigned short u[8]; short8 v; } o;
#pragma unroll
        for (int j = 0; j < 8; j++) {
            float f0 = __uint_as_float(((unsigned)(unsigned short)v0[j]) << 16);
            float f1 = __uint_as_float(((unsigned)(unsigned short)v1[j]) << 16);
            o.u[j] = f2bf(w0 * f0 + w1 * f1);
        }
        *(short8*)(o0 + flat) = o.v;
    }
}

// ---------------- launch ----------------
extern "C" void kernel_launch(void* const* d_in, const int* in_sizes, int n_in,
                              void* d_out, int out_size, void* d_ws, size_t ws_size,
                              hipStream_t stream) {
    const float* x      = (const float*)d_in[0];
    const float* qkv_w  = (const float*)d_in[1];
    const float* qkv_b  = (const float*)d_in[2];
    const float* proj_w = (const float*)d_in[3];
    const float* proj_b = (const float*)d_in[4];
    float* out = (float*)d_out;

    char* ws = (char*)d_ws;
    unsigned short* x_bf    = (unsigned short*)(ws);              // 12,582,912 B
    unsigned short* w1_bf   = (unsigned short*)(ws + 12582912);   //  3,538,944 B
    unsigned short* w2_bf   = (unsigned short*)(ws + 16121856);   //  1,179,648 B
    unsigned short* qkv_sep = (unsigned short*)(ws + 17301504);   // 37,748,736 B
    unsigned short* att     = (unsigned short*)(ws + 55050240);   // 12,582,912 B

    // after gemm<0>, x_bf and w1_bf are dead -> reuse for split-1 partial + (m,l)
    unsigned short* o_part1 = x_bf;
    float2*         ml      = (float2*)w1_bf;   // 2*2*12*4096*8 B = 1.57 MB

    cvt_swz<<<2048, 256, 0, stream>>>(x,      x_bf,  6291456 / 8);
    cvt_swz<<<864,  256, 0, stream>>>(qkv_w,  w1_bf, 1769472 / 8);
    cvt_swz<<<288,  256, 0, stream>>>(proj_w, w2_bf,  589824 / 8);

    gemm_bt<0, 128><<<dim3(18, 64), 256, 0, stream>>>(x_bf, w1_bf, qkv_b, qkv_sep,
                                                      8192, 2304, 768);

    attn_fwd<<<dim3(32, 24, 2), 256, 0, stream>>>(qkv_sep, att, o_part1, ml);
    attn_combine<<<2048, 256, 0, stream>>>(att, o_part1, ml, 6291456 / 8);

    gemm_bt<1, 64><<<dim3(12, 64), 256, 0, stream>>>(att, w2_bf, proj_b, out,
                                                     8192, 768, 768);
}